// Round 7
// baseline (270.617 us; speedup 1.0000x reference)
//
#include <hip/hip_runtime.h>
#include <hip/hip_bf16.h>
#include <stdint.h>

// HQQLinear: out = x @ dequant(W_q)^T + bias.
// (1) prep: x f32->bf16  +  W_q nibbles -> bf16 W_est   (single kernel)
// (2) 256x256x64 8-phase bf16 GEMM, 8 waves, 128KiB LDS dbuf,
//     counted vmcnt(6) 3-half-tile ledger, conflict-free chunk swizzle
//     slot(r,h)=r*4+(h^((r>>1)&3)), raw s_barrier, setprio, XCD swizzle.
//     THIS ROUND: T-loop unrolled x2 (compile-time dbuf index) + all stage/
//     ds_read addresses hoisted out of the loop (kill per-phase VALU remat).

#define IN_F  4096
#define OUT_F 4096
#define MROWS 4096

#define BM 256
#define BN 256
#define BK 64
#define NT (IN_F / BK)   // 64 K-tiles

typedef __attribute__((ext_vector_type(8))) __bf16 bf16x8;
typedef __attribute__((ext_vector_type(4))) float f32x4;

__device__ __forceinline__ ushort f2bf(float f) {
    uint32_t u = __float_as_uint(f);
    u += 0x7fffu + ((u >> 16) & 1u);   // RNE
    return (ushort)(u >> 16);
}

// ---------------- kernel 1: fused conv_x + dequant ----------------
#define CONV_BLK (MROWS * IN_F / 4 / 256)        // 16384
#define DQ_BLK   (32 * 262144 / 4 / 256)         // 8192

__global__ void prep(const float* __restrict__ x, ushort* __restrict__ xb,
                     const int* __restrict__ Wq, const float* __restrict__ scale,
                     const float* __restrict__ zero, ushort* __restrict__ West) {
    int blk = blockIdx.x;
    if (blk < CONV_BLK) {
        int i = (blk * 256 + threadIdx.x) * 4;
        float4 v = *(const float4*)(x + i);
        *(ushort4*)(xb + i) = make_ushort4(f2bf(v.x), f2bf(v.y), f2bf(v.z), f2bf(v.w));
    } else {
        int t = (blk - CONV_BLK) * 256 + threadIdx.x;
        int flat = t << 2;
        int p = flat >> 18;
        int c = flat & 262143;
        int j = c >> 12;
        int i = c & 4095;

        int4 q = *(const int4*)(Wq + flat);
        float4 sc = *(const float4*)(scale + c);
        float4 zr = *(const float4*)(zero + c);

        int   qv[4] = {q.x, q.y, q.z, q.w};
        float sv[4] = {sc.x, sc.y, sc.z, sc.w};
        float zv[4] = {zr.x, zr.y, zr.z, zr.w};

        ushort hi[4], lo[4];
#pragma unroll
        for (int e = 0; e < 4; ++e) {
            hi[e] = f2bf(((float)((qv[e] >> 4) & 0xF) - zv[e]) * sv[e]);
            lo[e] = f2bf(((float)(qv[e] & 0xF) - zv[e]) * sv[e]);
        }
        size_t o_hi = (size_t)(p * 64 + j) * IN_F + i;
        size_t o_lo = (size_t)((p + 32) * 64 + j) * IN_F + i;
        *(ushort4*)(West + o_hi) = make_ushort4(hi[0], hi[1], hi[2], hi[3]);
        *(ushort4*)(West + o_lo) = make_ushort4(lo[0], lo[1], lo[2], lo[3]);
    }
}

// ---------------- kernel 2: 256^2 8-phase bf16 GEMM ----------------
__device__ __forceinline__ void gload16(const ushort* g, const ushort* l) {
    __builtin_amdgcn_global_load_lds((const __attribute__((address_space(1))) void*)g,
                                     (__attribute__((address_space(3))) void*)l,
                                     16, 0, 0);
}

// LDS (ushort units): buf b at b*32768. A at +0, B at +16384.
// Within A/B: [khalf][1024 slots of 16B], khalf stride 8192 ushorts.
// slot(r,h) = r*4 + (h ^ ((r>>1)&3)), r = tile row 0..255, h = k-chunk 0..3.

#define VMCNT6 asm volatile("s_waitcnt vmcnt(6)" ::: "memory");
#define VMCNT0 asm volatile("s_waitcnt vmcnt(0)" ::: "memory");
#define BAR    __builtin_amdgcn_s_barrier();

// hoisted-base forms: bb/kk/mh/nb/kh/q are ALL compile-time literals.
// bf16x8 index units = 16B: khalf=1024, mh*64rows=256, 16rows=64.
#define DS_A(bb, kk, mh)                                                   \
    _Pragma("unroll") for (int mf = 0; mf < 4; ++mf)                       \
        afr[mf] = ap[bb][(kk) * 1024 + (mh) * 256 + mf * 64];

#define DS_B(bb, kk)                                                       \
    _Pragma("unroll") for (int nf = 0; nf < 4; ++nf)                       \
        bfr[nf] = bp[bb][(kk) * 1024 + nf * 64];

#define STAGE_A(nb, kh, kcol) {                                            \
    gload16(A + plA0 + (kcol), &lds[(nb)*32768 + (kh)*8192 + wave*512]);   \
    gload16(A + plA1 + (kcol), &lds[(nb)*32768 + (kh)*8192 + 4096 + wave*512]); }

#define STAGE_B(nb, kh, kcol) {                                            \
    gload16(B + plB0 + (kcol), &lds[(nb)*32768 + 16384 + (kh)*8192 + wave*512]); \
    gload16(B + plB1 + (kcol), &lds[(nb)*32768 + 16384 + (kh)*8192 + 4096 + wave*512]); }

#define MFMA16(mh)                                                                 \
    __builtin_amdgcn_s_setprio(1);                                                 \
    _Pragma("unroll") for (int mf = 0; mf < 4; ++mf)                               \
    _Pragma("unroll") for (int nf = 0; nf < 4; ++nf)                               \
        acc[(mh) * 4 + mf][nf] = __builtin_amdgcn_mfma_f32_16x16x32_bf16(          \
            afr[mf], bfr[nf], acc[(mh) * 4 + mf][nf], 0, 0, 0);                    \
    __builtin_amdgcn_s_setprio(0);

__global__ __launch_bounds__(512, 2) void gemm_bt(const ushort* __restrict__ A,
                                                  const ushort* __restrict__ B,
                                                  const float* __restrict__ bias,
                                                  float* __restrict__ C) {
    __shared__ alignas(16) ushort lds[65536];   // 128 KiB

    const int tid  = threadIdx.x;
    const int wave = tid >> 6;
    const int lane = tid & 63;
    const int rl   = lane & 15;                  // fragment row-in-16
    const int hh   = lane >> 4;                  // k-chunk
    const int hx   = hh ^ ((rl >> 1) & 3);       // swizzled chunk (read side)

    // XCD-aware swizzle (256 blocks, %8==0 -> bijective)
    int bid = blockIdx.x;
    int swz = (bid & 7) * 32 + (bid >> 3);
    const int m0 = (swz >> 4) * BM;
    const int n0 = (swz & 15) * BN;
    const int wr = wave >> 2;   // 0..1 -> 128 rows each
    const int wc = wave & 3;    // 0..3 -> 64 cols each

    f32x4 acc[8][4];
    f32x4 z4 = {0.f, 0.f, 0.f, 0.f};
#pragma unroll
    for (int i = 0; i < 8; ++i)
#pragma unroll
        for (int j = 0; j < 4; ++j) acc[i][j] = z4;

    // ---- hoisted per-lane stage source offsets (ushort units; <2^25) ----
    // q=0: s=wave*64+lane; q=1: s=512+wave*64+lane; r=s>>2; h=(s&3)^((r>>1)&3)
    uint plA0, plA1, plB0, plB1;
    {
        int s0 = wave * 64 + lane, r0 = s0 >> 2, h0 = (s0 & 3) ^ ((r0 >> 1) & 3);
        int s1 = 512 + wave * 64 + lane, r1 = s1 >> 2, h1 = (s1 & 3) ^ ((r1 >> 1) & 3);
        plA0 = (uint)((m0 + r0) * IN_F + h0 * 8);
        plA1 = (uint)((m0 + r1) * IN_F + h1 * 8);
        plB0 = (uint)((n0 + r0) * IN_F + h0 * 8);
        plB1 = (uint)((n0 + r1) * IN_F + h1 * 8);
    }

    // ---- hoisted LDS fragment base pointers (b=0 / b=1 copies) ----
    const uint abase = (uint)(((wr * 128 + rl) * 4 + hx) * 8);
    const uint bbase = (uint)(16384 + ((wc * 64 + rl) * 4 + hx) * 8);
    const bf16x8* ap[2] = { (const bf16x8*)&lds[abase],
                            (const bf16x8*)&lds[32768 + abase] };
    const bf16x8* bp[2] = { (const bf16x8*)&lds[bbase],
                            (const bf16x8*)&lds[32768 + bbase] };

    // prologue: tile0 fully + A(1,k0); drain tile0-k0 (vmcnt 10->6)
    STAGE_A(0, 0, 0u)
    STAGE_B(0, 0, 0u)
    STAGE_A(0, 1, 32u)
    STAGE_B(0, 1, 32u)
    STAGE_A(1, 0, (uint)BK)
    VMCNT6;
    BAR;

    // Steady-state ledger (2 loads/stage, per-wave vmcnt):
    //   T-1.ph3: A(T+1,k0) | T.ph0: B(T+1,k0) | T.ph1: A(T+1,k1)
    // | T.ph2: B(T+1,k1)   | T.ph3: A(T+2,k0)
    //   VMCNT6 @ph1 drains A(T,k1),B(T,k1) (read ph2/ph3);
    //   VMCNT6 @ph3 drains A(T+1,k0),B(T+1,k0) (read next ph0).
    //   WAR: ph3's A-stage targets regions last read 2 barriers earlier.
#pragma unroll 1
    for (int T = 0; T < NT; T += 2) {
        const uint kn1 = (uint)(((T + 1) & (NT - 1)) * BK);
        const uint kn2 = (uint)(((T + 2) & (NT - 1)) * BK);
        const uint kn3 = (uint)(((T + 3) & (NT - 1)) * BK);
        bf16x8 afr[4], bfr[4];

        // ---- sub-tile b=0 (reads buf0, stages into buf1 then buf0 @ph3) ----
        DS_B(0, 0) DS_A(0, 0, 0)
        STAGE_B(1, 0, kn1)
        BAR; MFMA16(0) BAR;

        DS_A(0, 0, 1)
        STAGE_A(1, 1, kn1 + 32)
        VMCNT6;
        BAR; MFMA16(1) BAR;

        DS_B(0, 1) DS_A(0, 1, 0)
        STAGE_B(1, 1, kn1 + 32)
        BAR; MFMA16(0) BAR;

        DS_A(0, 1, 1)
        STAGE_A(0, 0, kn2)
        VMCNT6;
        BAR; MFMA16(1) BAR;

        // ---- sub-tile b=1 (reads buf1, stages into buf0 then buf1 @ph3) ----
        DS_B(1, 0) DS_A(1, 0, 0)
        STAGE_B(0, 0, kn2)
        BAR; MFMA16(0) BAR;

        DS_A(1, 0, 1)
        STAGE_A(0, 1, kn2 + 32)
        VMCNT6;
        BAR; MFMA16(1) BAR;

        DS_B(1, 1) DS_A(1, 1, 0)
        STAGE_B(0, 1, kn2 + 32)
        BAR; MFMA16(0) BAR;

        DS_A(1, 1, 1)
        STAGE_A(1, 0, kn3)
        VMCNT6;
        BAR; MFMA16(1) BAR;
    }
    VMCNT0;   // don't exit with LDS-DMA in flight

    // epilogue: C = acc + bias. C/D map: col=lane&15, row=(lane>>4)*4+v
#pragma unroll
    for (int nf = 0; nf < 4; ++nf) {
        int col = n0 + wc * 64 + nf * 16 + rl;
        float bv = bias[col];
#pragma unroll
        for (int mfa = 0; mfa < 8; ++mfa) {
            int rbase = m0 + wr * 128 + mfa * 16 + (hh << 2);
#pragma unroll
            for (int v = 0; v < 4; ++v)
                C[(size_t)(rbase + v) * OUT_F + col] = acc[mfa][nf][v] + bv;
        }
    }
}

extern "C" void kernel_launch(void* const* d_in, const int* in_sizes, int n_in,
                              void* d_out, int out_size, void* d_ws, size_t ws_size,
                              hipStream_t stream) {
    const float* x     = (const float*)d_in[0];
    const int*   Wq    = (const int*)d_in[1];
    const float* scale = (const float*)d_in[2];
    const float* zero  = (const float*)d_in[3];
    const float* bias  = (const float*)d_in[4];
    float* out = (float*)d_out;

    ushort* xb   = (ushort*)d_ws;                            // 32 MB
    ushort* West = (ushort*)d_ws + (size_t)MROWS * IN_F;     // 32 MB

    prep<<<CONV_BLK + DQ_BLK, 256, 0, stream>>>(x, xb, Wq, scale, zero, West);
    gemm_bt<<<(MROWS / BM) * (OUT_F / BN), 512, 0, stream>>>(xb, West, bias, out);
}

// Round 8
// 269.379 us; speedup vs baseline: 1.0046x; 1.0046x over previous
//
#include <hip/hip_runtime.h>
#include <hip/hip_bf16.h>
#include <stdint.h>

// HQQLinear: out = x @ dequant(W_q)^T + bias.
// (1) prep: x f32->bf16  +  W_q nibbles -> bf16 W_est   (single kernel)
// (2) 256x256x64 8-phase bf16 GEMM, 8 waves, 128KiB LDS dbuf,
//     counted vmcnt(6) ledger, conflict-free chunk swizzle
//     slot(r,h)=r*4+(h^((r>>1)&3)), raw s_barrier, setprio, XCD swizzle.
//     THIS ROUND: ds_reads software-pipelined ONE PHASE AHEAD (af0/af1
//     ping-pong; bf0/bf1 reads shifted one phase early) so every fragment
//     is in registers before its phase's barrier opens -> LDS drain hides
//     under the previous MFMA region. sched_barrier(0) pins issue order.

#define IN_F  4096
#define OUT_F 4096
#define MROWS 4096

#define BM 256
#define BN 256
#define BK 64
#define NT (IN_F / BK)   // 64 K-tiles

typedef __attribute__((ext_vector_type(8))) __bf16 bf16x8;
typedef __attribute__((ext_vector_type(4))) float f32x4;

__device__ __forceinline__ ushort f2bf(float f) {
    uint32_t u = __float_as_uint(f);
    u += 0x7fffu + ((u >> 16) & 1u);   // RNE
    return (ushort)(u >> 16);
}

// ---------------- kernel 1: fused conv_x + dequant ----------------
#define CONV_BLK (MROWS * IN_F / 4 / 256)        // 16384
#define DQ_BLK   (32 * 262144 / 4 / 256)         // 8192

__global__ void prep(const float* __restrict__ x, ushort* __restrict__ xb,
                     const int* __restrict__ Wq, const float* __restrict__ scale,
                     const float* __restrict__ zero, ushort* __restrict__ West) {
    int blk = blockIdx.x;
    if (blk < CONV_BLK) {
        int i = (blk * 256 + threadIdx.x) * 4;
        float4 v = *(const float4*)(x + i);
        *(ushort4*)(xb + i) = make_ushort4(f2bf(v.x), f2bf(v.y), f2bf(v.z), f2bf(v.w));
    } else {
        int t = (blk - CONV_BLK) * 256 + threadIdx.x;
        int flat = t << 2;
        int p = flat >> 18;
        int c = flat & 262143;
        int j = c >> 12;
        int i = c & 4095;

        int4 q = *(const int4*)(Wq + flat);
        float4 sc = *(const float4*)(scale + c);
        float4 zr = *(const float4*)(zero + c);

        int   qv[4] = {q.x, q.y, q.z, q.w};
        float sv[4] = {sc.x, sc.y, sc.z, sc.w};
        float zv[4] = {zr.x, zr.y, zr.z, zr.w};

        ushort hi[4], lo[4];
#pragma unroll
        for (int e = 0; e < 4; ++e) {
            hi[e] = f2bf(((float)((qv[e] >> 4) & 0xF) - zv[e]) * sv[e]);
            lo[e] = f2bf(((float)(qv[e] & 0xF) - zv[e]) * sv[e]);
        }
        size_t o_hi = (size_t)(p * 64 + j) * IN_F + i;
        size_t o_lo = (size_t)((p + 32) * 64 + j) * IN_F + i;
        *(ushort4*)(West + o_hi) = make_ushort4(hi[0], hi[1], hi[2], hi[3]);
        *(ushort4*)(West + o_lo) = make_ushort4(lo[0], lo[1], lo[2], lo[3]);
    }
}

// ---------------- kernel 2: 256^2 8-phase bf16 GEMM ----------------
__device__ __forceinline__ void gload16(const ushort* g, const ushort* l) {
    __builtin_amdgcn_global_load_lds((const __attribute__((address_space(1))) void*)g,
                                     (__attribute__((address_space(3))) void*)l,
                                     16, 0, 0);
}

// LDS (ushort units): buf b at b*32768. A at +0, B at +16384.
// Within A/B: [khalf][1024 slots of 16B], khalf stride 8192 ushorts.
// slot(r,h) = r*4 + (h ^ ((r>>1)&3)), r = tile row 0..255, h = k-chunk 0..3.

#define VMCNT6 asm volatile("s_waitcnt vmcnt(6)" ::: "memory");
#define VMCNT0 asm volatile("s_waitcnt vmcnt(0)" ::: "memory");
#define BAR    __builtin_amdgcn_s_barrier();
#define SB0    __builtin_amdgcn_sched_barrier(0);

// bb/kk/mh/nb/kh all compile-time. bf16x8 index units = 16B.
#define RD_A(bb, kk, mh, DST)                                              \
    _Pragma("unroll") for (int mf = 0; mf < 4; ++mf)                       \
        DST[mf] = ap[bb][(kk) * 1024 + (mh) * 256 + mf * 64];

#define RD_B(bb, kk, DST)                                                  \
    _Pragma("unroll") for (int nf = 0; nf < 4; ++nf)                       \
        DST[nf] = bp[bb][(kk) * 1024 + nf * 64];

#define STAGE_A(nb, kh, kcol) {                                            \
    gload16(A + plA + (kcol), &lds[(nb)*32768 + (kh)*8192 + wave*512]);    \
    gload16(A + plA + 524288u + (kcol), &lds[(nb)*32768 + (kh)*8192 + 4096 + wave*512]); }

#define STAGE_B(nb, kh, kcol) {                                            \
    gload16(B + plB + (kcol), &lds[(nb)*32768 + 16384 + (kh)*8192 + wave*512]); \
    gload16(B + plB + 524288u + (kcol), &lds[(nb)*32768 + 16384 + (kh)*8192 + 4096 + wave*512]); }

#define MFMA16(mh, AF, BF)                                                         \
    __builtin_amdgcn_s_setprio(1);                                                 \
    _Pragma("unroll") for (int mf = 0; mf < 4; ++mf)                               \
    _Pragma("unroll") for (int nf = 0; nf < 4; ++nf)                               \
        acc[(mh) * 4 + mf][nf] = __builtin_amdgcn_mfma_f32_16x16x32_bf16(          \
            AF[mf], BF[nf], acc[(mh) * 4 + mf][nf], 0, 0, 0);                      \
    __builtin_amdgcn_s_setprio(0);

__global__ __launch_bounds__(512, 2) void gemm_bt(const ushort* __restrict__ A,
                                                  const ushort* __restrict__ B,
                                                  const float* __restrict__ bias,
                                                  float* __restrict__ C) {
    __shared__ alignas(16) ushort lds[65536];   // 128 KiB

    const int tid  = threadIdx.x;
    const int wave = tid >> 6;
    const int lane = tid & 63;
    const int rl   = lane & 15;                  // fragment row-in-16
    const int hh   = lane >> 4;                  // k-chunk
    const int hx   = hh ^ ((rl >> 1) & 3);       // swizzled chunk (read side)

    // XCD-aware swizzle (256 blocks, %8==0 -> bijective)
    int bid = blockIdx.x;
    int swz = (bid & 7) * 32 + (bid >> 3);
    const int m0 = (swz >> 4) * BM;
    const int n0 = (swz & 15) * BN;
    const int wr = wave >> 2;   // 0..1 -> 128 rows each
    const int wc = wave & 3;    // 0..3 -> 64 cols each

    f32x4 acc[8][4];
    f32x4 z4 = {0.f, 0.f, 0.f, 0.f};
#pragma unroll
    for (int i = 0; i < 8; ++i)
#pragma unroll
        for (int j = 0; j < 4; ++j) acc[i][j] = z4;

    // hoisted per-lane stage source offset (q=0; q=1 is +128*IN_F, h invariant)
    uint plA, plB;
    {
        int s0 = wave * 64 + lane, r0 = s0 >> 2, h0 = (s0 & 3) ^ ((r0 >> 1) & 3);
        plA = (uint)((m0 + r0) * IN_F + h0 * 8);
        plB = (uint)((n0 + r0) * IN_F + h0 * 8);
    }

    // hoisted LDS fragment base pointers (b=0 / b=1)
    const uint abase = (uint)(((wr * 128 + rl) * 4 + hx) * 8);
    const uint bbase = (uint)(16384 + ((wc * 64 + rl) * 4 + hx) * 8);
    const bf16x8* ap[2] = { (const bf16x8*)&lds[abase],
                            (const bf16x8*)&lds[32768 + abase] };
    const bf16x8* bp[2] = { (const bf16x8*)&lds[bbase],
                            (const bf16x8*)&lds[32768 + bbase] };

    // fragment register sets: af0/af1 ping-pong per phase, bf0/bf1 per k-half
    bf16x8 af0[4], af1[4], bf0[4], bf1[4];

    // prologue: tile0 fully + A(1,k0); drain tile0-k0 (vmcnt 10->6)
    STAGE_A(0, 0, 0u)
    STAGE_B(0, 0, 0u)
    STAGE_A(0, 1, 32u)
    STAGE_B(0, 1, 32u)
    STAGE_A(1, 0, (uint)BK)
    VMCNT6;
    BAR;
    RD_B(0, 0, bf0)      // fragments for P0 (data drained above)
    RD_A(0, 0, 0, af0)

    // Steady-state ledger (2 VM loads/stage, per-wave vmcnt; reads are DS, not VM):
    //   stages: P0:B(T+1,k0) P1:A(T+1,k1) P2:B(T+1,k1) P3:A(T+2,k0)
    //           P4:B(T+2,k0) P5:A(T+2,k1) P6:B(T+2,k1) P7:A(T+3,k0)
    //   VMCNT6 @P1/P3/P5/P7 drains exactly the k-half the reads just after it
    //   consume. All fragment reads issued one phase before their MFMA.
#pragma unroll 1
    for (int T = 0; T < NT; T += 2) {
        const uint kn1 = (uint)(((T + 1) & (NT - 1)) * BK);
        const uint kn2 = (uint)(((T + 2) & (NT - 1)) * BK);
        const uint kn3 = (uint)(((T + 3) & (NT - 1)) * BK);

        // P0: compute buf0-k0 mh0
        RD_A(0, 0, 1, af1)
        STAGE_B(1, 0, kn1)
        SB0 BAR; MFMA16(0, af0, bf0) BAR;

        // P1: buf0-k0 mh1
        STAGE_A(1, 1, kn1 + 32)
        VMCNT6;
        RD_B(0, 1, bf1) RD_A(0, 1, 0, af0)
        SB0 BAR; MFMA16(1, af1, bf0) BAR;

        // P2: buf0-k1 mh0
        RD_A(0, 1, 1, af1)
        STAGE_B(1, 1, kn1 + 32)
        SB0 BAR; MFMA16(0, af0, bf1) BAR;

        // P3: buf0-k1 mh1
        STAGE_A(0, 0, kn2)
        VMCNT6;
        RD_B(1, 0, bf0) RD_A(1, 0, 0, af0)
        SB0 BAR; MFMA16(1, af1, bf1) BAR;

        // P4: buf1-k0 mh0
        RD_A(1, 0, 1, af1)
        STAGE_B(0, 0, kn2)
        SB0 BAR; MFMA16(0, af0, bf0) BAR;

        // P5: buf1-k0 mh1
        STAGE_A(0, 1, kn2 + 32)
        VMCNT6;
        RD_B(1, 1, bf1) RD_A(1, 1, 0, af0)
        SB0 BAR; MFMA16(1, af1, bf0) BAR;

        // P6: buf1-k1 mh0
        RD_A(1, 1, 1, af1)
        STAGE_B(0, 1, kn2 + 32)
        SB0 BAR; MFMA16(0, af0, bf1) BAR;

        // P7: buf1-k1 mh1
        STAGE_A(1, 0, kn3)
        VMCNT6;
        RD_B(0, 0, bf0) RD_A(0, 0, 0, af0)   // for next iter's P0
        SB0 BAR; MFMA16(1, af1, bf1) BAR;
    }
    VMCNT0;   // don't exit with LDS-DMA in flight

    // epilogue: C = acc + bias. C/D map: col=lane&15, row=(lane>>4)*4+v
#pragma unroll
    for (int nf = 0; nf < 4; ++nf) {
        int col = n0 + wc * 64 + nf * 16 + rl;
        float bv = bias[col];
#pragma unroll
        for (int mfa = 0; mfa < 8; ++mfa) {
            int rbase = m0 + wr * 128 + mfa * 16 + (hh << 2);
#pragma unroll
            for (int v = 0; v < 4; ++v)
                C[(size_t)(rbase + v) * OUT_F + col] = acc[mfa][nf][v] + bv;
        }
    }
}

extern "C" void kernel_launch(void* const* d_in, const int* in_sizes, int n_in,
                              void* d_out, int out_size, void* d_ws, size_t ws_size,
                              hipStream_t stream) {
    const float* x     = (const float*)d_in[0];
    const int*   Wq    = (const int*)d_in[1];
    const float* scale = (const float*)d_in[2];
    const float* zero  = (const float*)d_in[3];
    const float* bias  = (const float*)d_in[4];
    float* out = (float*)d_out;

    ushort* xb   = (ushort*)d_ws;                            // 32 MB
    ushort* West = (ushort*)d_ws + (size_t)MROWS * IN_F;     // 32 MB

    prep<<<CONV_BLK + DQ_BLK, 256, 0, stream>>>(x, xb, Wq, scale, zero, West);
    gemm_bt<<<(MROWS / BM) * (OUT_F / BN), 512, 0, stream>>>(xb, West, bias, out);
}

// Round 9
// 264.303 us; speedup vs baseline: 1.0239x; 1.0192x over previous
//
#include <hip/hip_runtime.h>
#include <hip/hip_bf16.h>
#include <stdint.h>

// HQQLinear: out = x @ dequant(W_q)^T + bias.
// (1) prep: x f32->bf16  +  W_q nibbles -> bf16 W_est   (single kernel)
// (2) 256x256x64 bf16 GEMM, 8 waves, 128KiB LDS dbuf, conflict-free chunk
//     swizzle slot(r,h)=r*4+(h^((r>>1)&3)), XCD block swizzle.
//     THIS ROUND: SINGLE-BARRIER phase bodies:
//       [MFMA(p) | ds_reads(p+1) | stage-issue | vmcnt(4) | BAR]
//     so reads/stage/VALU issue while the MFMA pipe crunches (separate
//     pipes) instead of sitting in a barrier-serialized stage region.
//     Ledger: 1 stage-job(2 loads)/body; at even-body ends exactly 4 jobs
//     in flight -> vmcnt(4) drains exactly the half read next body.

#define IN_F  4096
#define OUT_F 4096
#define MROWS 4096

#define BM 256
#define BN 256
#define BK 64
#define NT (IN_F / BK)   // 64 K-tiles

typedef __attribute__((ext_vector_type(8))) __bf16 bf16x8;
typedef __attribute__((ext_vector_type(4))) float f32x4;

__device__ __forceinline__ ushort f2bf(float f) {
    uint32_t u = __float_as_uint(f);
    u += 0x7fffu + ((u >> 16) & 1u);   // RNE
    return (ushort)(u >> 16);
}

// ---------------- kernel 1: fused conv_x + dequant ----------------
#define CONV_BLK (MROWS * IN_F / 4 / 256)        // 16384
#define DQ_BLK   (32 * 262144 / 4 / 256)         // 8192

__global__ void prep(const float* __restrict__ x, ushort* __restrict__ xb,
                     const int* __restrict__ Wq, const float* __restrict__ scale,
                     const float* __restrict__ zero, ushort* __restrict__ West) {
    int blk = blockIdx.x;
    if (blk < CONV_BLK) {
        int i = (blk * 256 + threadIdx.x) * 4;
        float4 v = *(const float4*)(x + i);
        *(ushort4*)(xb + i) = make_ushort4(f2bf(v.x), f2bf(v.y), f2bf(v.z), f2bf(v.w));
    } else {
        int t = (blk - CONV_BLK) * 256 + threadIdx.x;
        int flat = t << 2;
        int p = flat >> 18;
        int c = flat & 262143;
        int j = c >> 12;
        int i = c & 4095;

        int4 q = *(const int4*)(Wq + flat);
        float4 sc = *(const float4*)(scale + c);
        float4 zr = *(const float4*)(zero + c);

        int   qv[4] = {q.x, q.y, q.z, q.w};
        float sv[4] = {sc.x, sc.y, sc.z, sc.w};
        float zv[4] = {zr.x, zr.y, zr.z, zr.w};

        ushort hi[4], lo[4];
#pragma unroll
        for (int e = 0; e < 4; ++e) {
            hi[e] = f2bf(((float)((qv[e] >> 4) & 0xF) - zv[e]) * sv[e]);
            lo[e] = f2bf(((float)(qv[e] & 0xF) - zv[e]) * sv[e]);
        }
        size_t o_hi = (size_t)(p * 64 + j) * IN_F + i;
        size_t o_lo = (size_t)((p + 32) * 64 + j) * IN_F + i;
        *(ushort4*)(West + o_hi) = make_ushort4(hi[0], hi[1], hi[2], hi[3]);
        *(ushort4*)(West + o_lo) = make_ushort4(lo[0], lo[1], lo[2], lo[3]);
    }
}

// ---------------- kernel 2: 256^2 single-barrier-phase bf16 GEMM ----------------
__device__ __forceinline__ void gload16(const ushort* g, const ushort* l) {
    __builtin_amdgcn_global_load_lds((const __attribute__((address_space(1))) void*)g,
                                     (__attribute__((address_space(3))) void*)l,
                                     16, 0, 0);
}

// LDS (ushort units): buf b at b*32768. A at +0, B at +16384.
// Within A/B: [khalf][1024 slots of 16B], khalf stride 8192 ushorts.
// slot(r,h) = r*4 + (h ^ ((r>>1)&3)), r = tile row 0..255, h = k-chunk 0..3.

#define VMCNT4 asm volatile("s_waitcnt vmcnt(4)" ::: "memory");
#define VMCNT6 asm volatile("s_waitcnt vmcnt(6)" ::: "memory");
#define VMCNT0 asm volatile("s_waitcnt vmcnt(0)" ::: "memory");
#define BAR    __builtin_amdgcn_s_barrier();
#define SB0    __builtin_amdgcn_sched_barrier(0);

// bb/kk/mh all compile-time. bf16x8 index units = 16B.
#define RD_A(bb, kk, mh, DST)                                              \
    _Pragma("unroll") for (int mf = 0; mf < 4; ++mf)                       \
        DST[mf] = ap[bb][(kk) * 1024 + (mh) * 256 + mf * 64];

#define RD_B(bb, kk, DST)                                                  \
    _Pragma("unroll") for (int nf = 0; nf < 4; ++nf)                       \
        DST[nf] = bp[bb][(kk) * 1024 + nf * 64];

#define STAGE_A(nb, kh, kcol) {                                            \
    gload16(A + plA + (kcol), &lds[(nb)*32768 + (kh)*8192 + wave*512]);    \
    gload16(A + plA + 524288u + (kcol), &lds[(nb)*32768 + (kh)*8192 + 4096 + wave*512]); }

#define STAGE_B(nb, kh, kcol) {                                            \
    gload16(B + plB + (kcol), &lds[(nb)*32768 + 16384 + (kh)*8192 + wave*512]); \
    gload16(B + plB + 524288u + (kcol), &lds[(nb)*32768 + 16384 + (kh)*8192 + 4096 + wave*512]); }

#define MFMA16(mh, AF, BF)                                                         \
    __builtin_amdgcn_s_setprio(1);                                                 \
    _Pragma("unroll") for (int mf = 0; mf < 4; ++mf)                               \
    _Pragma("unroll") for (int nf = 0; nf < 4; ++nf)                               \
        acc[(mh) * 4 + mf][nf] = __builtin_amdgcn_mfma_f32_16x16x32_bf16(          \
            AF[mf], BF[nf], acc[(mh) * 4 + mf][nf], 0, 0, 0);                      \
    __builtin_amdgcn_s_setprio(0);

__global__ __launch_bounds__(512, 2) void gemm_bt(const ushort* __restrict__ A,
                                                  const ushort* __restrict__ B,
                                                  const float* __restrict__ bias,
                                                  float* __restrict__ C) {
    __shared__ alignas(16) ushort lds[65536];   // 128 KiB

    const int tid  = threadIdx.x;
    const int wave = tid >> 6;
    const int lane = tid & 63;
    const int rl   = lane & 15;                  // fragment row-in-16
    const int hh   = lane >> 4;                  // k-chunk
    const int hx   = hh ^ ((rl >> 1) & 3);       // swizzled chunk (read side)

    // XCD-aware swizzle (256 blocks, %8==0 -> bijective)
    int bid = blockIdx.x;
    int swz = (bid & 7) * 32 + (bid >> 3);
    const int m0 = (swz >> 4) * BM;
    const int n0 = (swz & 15) * BN;
    const int wr = wave >> 2;   // 0..1 -> 128 rows each
    const int wc = wave & 3;    // 0..3 -> 64 cols each

    f32x4 acc[8][4];
    f32x4 z4 = {0.f, 0.f, 0.f, 0.f};
#pragma unroll
    for (int i = 0; i < 8; ++i)
#pragma unroll
        for (int j = 0; j < 4; ++j) acc[i][j] = z4;

    // hoisted per-lane stage source offset (q=0; q=1 is +128*IN_F, h invariant)
    uint plA, plB;
    {
        int s0 = wave * 64 + lane, r0 = s0 >> 2, h0 = (s0 & 3) ^ ((r0 >> 1) & 3);
        plA = (uint)((m0 + r0) * IN_F + h0 * 8);
        plB = (uint)((n0 + r0) * IN_F + h0 * 8);
    }

    // hoisted LDS fragment base pointers (b=0 / b=1)
    const uint abase = (uint)(((wr * 128 + rl) * 4 + hx) * 8);
    const uint bbase = (uint)(16384 + ((wc * 64 + rl) * 4 + hx) * 8);
    const bf16x8* ap[2] = { (const bf16x8*)&lds[abase],
                            (const bf16x8*)&lds[32768 + abase] };
    const bf16x8* bp[2] = { (const bf16x8*)&lds[bbase],
                            (const bf16x8*)&lds[32768 + bbase] };

    // fragment register sets: af0/af1 ping-pong per phase, bf0/bf1 per k-half
    bf16x8 af0[4], af1[4], bf0[4], bf1[4];

    // prologue: 5 stage jobs; vmcnt(6) drains jobs 1,2 = (buf0,k0) A,B
    STAGE_A(0, 0, 0u)          // job1
    STAGE_B(0, 0, 0u)          // job2
    STAGE_A(0, 1, 32u)         // job3
    STAGE_B(0, 1, 32u)         // job4
    STAGE_A(1, 0, (uint)BK)    // job5
    VMCNT6;
    BAR;
    RD_B(0, 0, bf0)            // (buf0,k0) fragments for P0's MFMA
    RD_A(0, 0, 0, af0)

    // Single-barrier bodies. Stage stream (1 job/body):
    //   P0:B(T+1,k0) P1:A(T+1,k1) P2:B(T+1,k1) P3:A(T+2,k0)
    //   P4:B(T+2,k0) P5:A(T+2,k1) P6:B(T+2,k1) P7:A(T+3,k0)
    // Invariant: at even-body end exactly 4 jobs (8 loads) outstanding;
    // vmcnt(4) there drains exactly the half read in the next body.
#pragma unroll 1
    for (int T = 0; T < NT; T += 2) {
        const uint kn1 = (uint)(((T + 1) & (NT - 1)) * BK);   // wraps at tail
        const uint kn2 = (uint)(((T + 2) & (NT - 1)) * BK);
        const uint kn3 = (uint)(((T + 3) & (NT - 1)) * BK);

        // P0: tile T, k0, mh0
        MFMA16(0, af0, bf0)
        RD_A(0, 0, 1, af1)
        STAGE_B(1, 0, kn1)
        VMCNT4 SB0 BAR;

        // P1: k0, mh1
        MFMA16(1, af1, bf0)
        RD_B(0, 1, bf1) RD_A(0, 1, 0, af0)
        STAGE_A(1, 1, kn1 + 32)
        SB0 BAR;

        // P2: k1, mh0
        MFMA16(0, af0, bf1)
        RD_A(0, 1, 1, af1)
        STAGE_B(1, 1, kn1 + 32)
        VMCNT4 SB0 BAR;

        // P3: k1, mh1
        MFMA16(1, af1, bf1)
        RD_B(1, 0, bf0) RD_A(1, 0, 0, af0)
        STAGE_A(0, 0, kn2)
        SB0 BAR;

        // P4: tile T+1, k0, mh0
        MFMA16(0, af0, bf0)
        RD_A(1, 0, 1, af1)
        STAGE_B(0, 0, kn2)
        VMCNT4 SB0 BAR;

        // P5: k0, mh1
        MFMA16(1, af1, bf0)
        RD_B(1, 1, bf1) RD_A(1, 1, 0, af0)
        STAGE_A(0, 1, kn2 + 32)
        SB0 BAR;

        // P6: k1, mh0
        MFMA16(0, af0, bf1)
        RD_A(1, 1, 1, af1)
        STAGE_B(0, 1, kn2 + 32)
        VMCNT4 SB0 BAR;

        // P7: k1, mh1  (+ reads (buf0,k0) for next iteration's P0)
        MFMA16(1, af1, bf1)
        RD_B(0, 0, bf0) RD_A(0, 0, 0, af0)
        STAGE_A(1, 0, kn3)
        SB0 BAR;
    }
    VMCNT0;   // don't exit with LDS-DMA in flight

    // epilogue: C = acc + bias. C/D map: col=lane&15, row=(lane>>4)*4+v
#pragma unroll
    for (int nf = 0; nf < 4; ++nf) {
        int col = n0 + wc * 64 + nf * 16 + rl;
        float bv = bias[col];
#pragma unroll
        for (int mfa = 0; mfa < 8; ++mfa) {
            int rbase = m0 + wr * 128 + mfa * 16 + (hh << 2);
#pragma unroll
            for (int v = 0; v < 4; ++v)
                C[(size_t)(rbase + v) * OUT_F + col] = acc[mfa][nf][v] + bv;
        }
    }
}

extern "C" void kernel_launch(void* const* d_in, const int* in_sizes, int n_in,
                              void* d_out, int out_size, void* d_ws, size_t ws_size,
                              hipStream_t stream) {
    const float* x     = (const float*)d_in[0];
    const int*   Wq    = (const int*)d_in[1];
    const float* scale = (const float*)d_in[2];
    const float* zero  = (const float*)d_in[3];
    const float* bias  = (const float*)d_in[4];
    float* out = (float*)d_out;

    ushort* xb   = (ushort*)d_ws;                            // 32 MB
    ushort* West = (ushort*)d_ws + (size_t)MROWS * IN_F;     // 32 MB

    prep<<<CONV_BLK + DQ_BLK, 256, 0, stream>>>(x, xb, Wq, scale, zero, West);
    gemm_bt<<<(MROWS / BM) * (OUT_F / BN), 512, 0, stream>>>(xb, West, bias, out);
}